// Round 13
// baseline (1117.508 us; speedup 1.0000x reference)
//
#include <hip/hip_runtime.h>
#include <hip/hip_bf16.h>
#include <stdint.h>

#define TOKS 16384
#define HDIM 2048
#define IDIM 1024
#define NEXP 8
#define TOPK 2
#define NPAIR (TOKS*TOPK)   // 32768

typedef __attribute__((ext_vector_type(4))) float f32x4;
typedef __attribute__((ext_vector_type(8))) __bf16 bf16x8;
typedef __attribute__((ext_vector_type(8))) unsigned short u16x8;

#define GLOAD_LDS16(gp, lp) \
  __builtin_amdgcn_global_load_lds((const __attribute__((address_space(1))) void*)(gp), \
                                   (__attribute__((address_space(3))) void*)(lp), 16, 0, 0)

#define LGKM_WAITN(n) asm volatile("s_waitcnt lgkmcnt(" #n ")" ::: "memory")
#define VM_WAITN(n)   asm volatile("s_waitcnt vmcnt(" #n ")" ::: "memory")
#define SBAR0()       __builtin_amdgcn_sched_barrier(0)

__device__ __forceinline__ unsigned short f2bf(float f) {
  unsigned int u = __float_as_uint(f);
  u += 0x7FFF + ((u >> 16) & 1);   // RNE
  return (unsigned short)(u >> 16);
}
__device__ __forceinline__ float bf2f(unsigned short h) {
  return __uint_as_float(((unsigned int)h) << 16);
}

// ---------------- fused conversion: f32 -> bf16 for w13, w2, x ----------------
#define W13_N8 (NEXP * 2 * IDIM * HDIM / 8)   // 4194304
#define W2_N8  (NEXP * HDIM * IDIM / 8)       // 2097152
#define X_N8   (TOKS * HDIM / 8)              // 4194304
__global__ __launch_bounds__(256) void cvt_all(const float* __restrict__ w13,
                                               const float* __restrict__ w2,
                                               const float* __restrict__ x,
                                               unsigned short* __restrict__ w13b,
                                               unsigned short* __restrict__ w2b,
                                               unsigned short* __restrict__ xb) {
  int i = blockIdx.x * 256 + threadIdx.x;
  const float* s; unsigned short* d; int j;
  if (i < W13_N8)              { s = w13; d = w13b; j = i; }
  else if (i < W13_N8 + W2_N8) { s = w2;  d = w2b;  j = i - W13_N8; }
  else                         { s = x;   d = xb;   j = i - W13_N8 - W2_N8; }
  const float4* sp = (const float4*)s + (size_t)j * 2;
  float4 a = sp[0], b = sp[1];
  u16x8 o;
  o[0] = f2bf(a.x); o[1] = f2bf(a.y); o[2] = f2bf(a.z); o[3] = f2bf(a.w);
  o[4] = f2bf(b.x); o[5] = f2bf(b.y); o[6] = f2bf(b.z); o[7] = f2bf(b.w);
  *((u16x8*)d + j) = o;
}

// ---------------- routing ----------------
// ctrl ints: [0..7]=counts [8..15]=offsets [16..23]=cursors [24..31]=rowtile prefix [32]=total tiles
__global__ void route_count(const int* __restrict__ ert, int* __restrict__ ctrl) {
  int p = blockIdx.x * 256 + threadIdx.x;
  if (p < NPAIR) atomicAdd(&ctrl[ert[p]], 1);
}

__global__ void route_scan(int* __restrict__ ctrl) {
  if (blockIdx.x == 0 && threadIdx.x == 0) {
    int off = 0;
    for (int e = 0; e < NEXP; ++e) { ctrl[8 + e] = off; ctrl[16 + e] = off; off += ctrl[e]; }
    int toff = 0;
    for (int e = 0; e < NEXP; ++e) { ctrl[24 + e] = toff; toff += (ctrl[e] + 255) >> 8; }
    ctrl[32] = toff;
  }
}

__global__ void route_scatter(const int* __restrict__ ert, const float* __restrict__ rw,
                              int* __restrict__ ctrl, int* __restrict__ porig,
                              float* __restrict__ pcoef, int* __restrict__ pinv) {
  int p = blockIdx.x * 256 + threadIdx.x;
  if (p < NPAIR) {
    int e = ert[p];
    int pos = atomicAdd(&ctrl[16 + e], 1);
    porig[pos] = p;
    pcoef[pos] = rw[p];
    pinv[p]    = pos;
  }
}

// ===== GEMM: 256x256 block tile, 8 waves (2M x 4N), per-wave 128x64, BK=32.
// A (gathered, 6x LDS amplification) staged via global_load_lds into a 4-deep
// 16 KB ring (64 KB), XOR-swizzled. B (streaming weights) loaded DIRECTLY
// global->VGPR per-lane (flatmm style): halves the LDS-pipe traffic (the
// measured binding resource, rounds 6-12) and needs no barrier protection.
// vmcnt ledger per iter i (issue order: STAGE_A(i+3)=2, LOADB(i+1)=4):
//   before q0: VM(6) retires B(i) AND A(i+1) [older]  -> tails 4 / 0.
//   mid-iter barrier makes A(i+1) cross-wave visible before RD_A(buf i+1);
//   buf(i+3)&3 overwrite safe: its prior reads retired at iter(i-1) lgkm(0)
//   before that iter's barrier.  lgkm: RD_A = A0(4),A1(4): waits 4 / 0.

#define RD_A(lb, A0v, A1v) do {                                                      \
  _Pragma("unroll") for (int mi = 0; mi < 4; ++mi) {                                 \
    int r_ = wr * 128 + mi * 16 + l15;                                               \
    A0v[mi] = *(const bf16x8*)((lb) + r_ * 64 + ((l16 ^ ((r_ >> 1) & 3)) << 4)); }   \
  _Pragma("unroll") for (int mi = 0; mi < 4; ++mi) {                                 \
    int r_ = wr * 128 + 64 + mi * 16 + l15;                                          \
    A1v[mi] = *(const bf16x8*)((lb) + r_ * 64 + ((l16 ^ ((r_ >> 1) & 3)) << 4)); }   \
} while (0)

#define LOADB(i, B) do {                                                             \
  B[0][0] = *(const bf16x8*)(gB00 + (size_t)(i) * 32);                               \
  B[0][1] = *(const bf16x8*)(gB01 + (size_t)(i) * 32);                               \
  B[1][0] = *(const bf16x8*)(gB10 + (size_t)(i) * 32);                               \
  B[1][1] = *(const bf16x8*)(gB11 + (size_t)(i) * 32);                               \
} while (0)

#define MMQ(qm, qn, Av, Bv) do {                                                     \
  __builtin_amdgcn_s_setprio(1);                                                     \
  _Pragma("unroll") for (int mi = 0; mi < 4; ++mi)                                   \
    _Pragma("unroll") for (int ni = 0; ni < 2; ++ni)                                 \
      acc[qm][qn][mi][ni] = __builtin_amdgcn_mfma_f32_16x16x32_bf16(                 \
          Av[mi], Bv[ni], acc[qm][qn][mi][ni], 0, 0, 0);                             \
  __builtin_amdgcn_s_setprio(0);                                                     \
} while (0)

#define ITER(i, cA0, cA1, cB, nA0, nA1, nB) do {                                     \
  if ((i) + 3 < NT) STAGE((i) + 3);                                                  \
  if ((i) + 1 < NT) LOADB((i) + 1, nB);                                              \
  if ((i) < NT - 3)      { VM_WAITN(6); }                                            \
  else if ((i) < NT - 1) { VM_WAITN(4); }                                            \
  else                   { VM_WAITN(0); }                                            \
  SBAR0();                                                                           \
  LGKM_WAITN(4); SBAR0();                                                            \
  MMQ(0, 0, cA0, (cB)[0]);                                                           \
  MMQ(0, 1, cA0, (cB)[1]);                                                           \
  LGKM_WAITN(0); SBAR0();                                                            \
  MMQ(1, 0, cA1, (cB)[0]);                                                           \
  if ((i) < NT - 1) {                                                                \
    __builtin_amdgcn_s_barrier();                                                    \
    SBAR0();                                                                         \
    RD_A(lds + (((i) + 1) & 3) * 16384, nA0, nA1);                                   \
    SBAR0();                                                                         \
  }                                                                                  \
  MMQ(1, 1, cA1, (cB)[1]);                                                           \
} while (0)

#define GEMM_BODY() do {                                                             \
  STAGE(0); STAGE(1); STAGE(2);                                                      \
  LOADB(0, Bc);                                                                      \
  VM_WAITN(8);                       /* retire tile 0 (keep S1,S2,B0) */             \
  __builtin_amdgcn_s_barrier();                                                      \
  SBAR0();                                                                           \
  RD_A(lds, A0a, A1a);                                                               \
  SBAR0();                                                                           \
  for (int i = 0; i < NT; i += 2) {                                                  \
    ITER(i,     A0a, A1a, Bc, A0b, A1b, Bn);                                         \
    ITER(i + 1, A0b, A1b, Bn, A0a, A1a, Bc);                                         \
  }                                                                                  \
} while (0)

// XCD-co-located block map: the 8 cb-blocks of one tile occupy 8 consecutive
// dispatch slots of the SAME XCD (bid = x + 8*(tg*8+cb), tile = tg*8+x).
#define TILE_MAP()                                                                   \
  const int x_ = bid & 7, k_ = bid >> 3;                                             \
  const int cb = k_ & 7;                                                             \
  const int tile = ((k_ >> 3) << 3) + x_;

// ============ GEMM1: act = silu(x@Wg^T)*(x@Wu^T) ============
__global__ __launch_bounds__(512, 2) void gemm1(const unsigned short* __restrict__ xb,
                                                const unsigned short* __restrict__ w13b,
                                                const int* __restrict__ ctrl,
                                                const int* __restrict__ porig,
                                                unsigned short* __restrict__ actb) {
  __shared__ __align__(16) char lds[65536];
  const int bid  = blockIdx.x;
  TILE_MAP();
  if (tile >= ctrl[32]) return;
  int e = 7;
  #pragma unroll
  for (int k = 7; k >= 1; --k) if (tile < ctrl[24 + k]) e = k - 1;
  const int Ne   = ctrl[e];
  const int base = ctrl[8 + e];
  const int row0 = (tile - ctrl[24 + e]) * 256;
  const int c0   = cb * 128;
  const int tid  = threadIdx.x;
  const int wid  = tid >> 6;
  const int lane = tid & 63;
  const int wr   = wid >> 2;          // 0..1
  const int wc   = wid & 3;           // 0..3
  const int l15  = lane & 15;
  const int l16  = lane >> 4;
  const int NT   = HDIM / 32;         // 64

  // A staging pointers (source pre-swizzled): row = wid*16 + (lane>>2)
  const unsigned short *gA0, *gA1;
  {
    int rl = wid * 16 + (lane >> 2);
    int r0 = rl, r1 = 128 + rl;
    int c80 = (lane & 3) ^ ((r0 >> 1) & 3);
    int c81 = (lane & 3) ^ ((r1 >> 1) & 3);
    int rr0 = row0 + r0; if (rr0 > Ne - 1) rr0 = Ne - 1;
    int rr1 = row0 + r1; if (rr1 > Ne - 1) rr1 = Ne - 1;
    gA0 = xb + (size_t)(porig[base + rr0] >> 1) * HDIM + c80 * 8;
    gA1 = xb + (size_t)(porig[base + rr1] >> 1) * HDIM + c81 * 8;
  }
  // B fragment pointers, direct global (natural layout, no swizzle):
  // frag (qn,ni): w13 row = (qn?IDIM:0) + act_col;  act_col = c0+wc*32+ni*16+l15
  const unsigned short *gB00, *gB01, *gB10, *gB11;
  {
    int colb = c0 + wc * 32 + l15;
    gB00 = w13b + ((size_t)e * 2 * IDIM + colb)             * HDIM + l16 * 8;
    gB01 = w13b + ((size_t)e * 2 * IDIM + colb + 16)        * HDIM + l16 * 8;
    gB10 = w13b + ((size_t)e * 2 * IDIM + IDIM + colb)      * HDIM + l16 * 8;
    gB11 = w13b + ((size_t)e * 2 * IDIM + IDIM + colb + 16) * HDIM + l16 * 8;
  }

  f32x4 acc[2][2][4][2];
  #pragma unroll
  for (int qm = 0; qm < 2; ++qm)
    #pragma unroll
    for (int qn = 0; qn < 2; ++qn)
      #pragma unroll
      for (int mi = 0; mi < 4; ++mi)
        #pragma unroll
        for (int ni = 0; ni < 2; ++ni) acc[qm][qn][mi][ni] = (f32x4)(0.0f);

  auto STAGE = [&](int kt) {
    char* d = lds + (kt & 3) * 16384 + wid * 1024;
    GLOAD_LDS16(gA0 + kt * 32, d);
    GLOAD_LDS16(gA1 + kt * 32, d + 8192);
  };

  bf16x8 A0a[4], A1a[4], A0b[4], A1b[4];
  bf16x8 Bc[2][2], Bn[2][2];

  GEMM_BODY();

  // epilogue: silu(gate)*up -> bf16 act (qn=0 gate, qn=1 up, same cols)
  #pragma unroll
  for (int qm = 0; qm < 2; ++qm)
    #pragma unroll
    for (int mi = 0; mi < 4; ++mi)
      #pragma unroll
      for (int jj = 0; jj < 4; ++jj) {
        int r = wr * 128 + qm * 64 + mi * 16 + l16 * 4 + jj;
        int rr = row0 + r;
        if (rr < Ne) {
          #pragma unroll
          for (int ni = 0; ni < 2; ++ni) {
            float g = acc[qm][0][mi][ni][jj];
            float u = acc[qm][1][mi][ni][jj];
            float a = g / (1.0f + __expf(-g)) * u;
            actb[(size_t)(base + rr) * IDIM + (c0 + wc * 32 + ni * 16 + l15)] = f2bf(a);
          }
        }
      }
}

// ============ GEMM2: yb[pos] = coef * (act @ w2^T) ============
__global__ __launch_bounds__(512, 2) void gemm2(const unsigned short* __restrict__ actb,
                                                const unsigned short* __restrict__ w2b,
                                                const int* __restrict__ ctrl,
                                                const float* __restrict__ pcoef,
                                                unsigned short* __restrict__ yb) {
  __shared__ __align__(16) char lds[65536];
  const int bid  = blockIdx.x;
  TILE_MAP();
  if (tile >= ctrl[32]) return;
  int e = 7;
  #pragma unroll
  for (int k = 7; k >= 1; --k) if (tile < ctrl[24 + k]) e = k - 1;
  const int Ne   = ctrl[e];
  const int base = ctrl[8 + e];
  const int row0 = (tile - ctrl[24 + e]) * 256;
  const int n0   = cb * 256;
  const int tid  = threadIdx.x;
  const int wid  = tid >> 6;
  const int lane = tid & 63;
  const int wr   = wid >> 2;
  const int wc   = wid & 3;
  const int l15  = lane & 15;
  const int l16  = lane >> 4;
  const int NT   = IDIM / 32;         // 32

  const unsigned short *gA0, *gA1;
  {
    int rl = wid * 16 + (lane >> 2);
    int r0 = rl, r1 = 128 + rl;
    int c80 = (lane & 3) ^ ((r0 >> 1) & 3);
    int c81 = (lane & 3) ^ ((r1 >> 1) & 3);
    int rr0 = row0 + r0; if (rr0 > Ne - 1) rr0 = Ne - 1;
    int rr1 = row0 + r1; if (rr1 > Ne - 1) rr1 = Ne - 1;
    gA0 = actb + (size_t)(base + rr0) * IDIM + c80 * 8;
    gA1 = actb + (size_t)(base + rr1) * IDIM + c81 * 8;
  }
  // B frag (qn,ni): w2 row = n0 + wc*64 + qn*32 + ni*16 + l15
  const unsigned short *gB00, *gB01, *gB10, *gB11;
  {
    int rowb = n0 + wc * 64 + l15;
    gB00 = w2b + ((size_t)e * HDIM + rowb)      * IDIM + l16 * 8;
    gB01 = w2b + ((size_t)e * HDIM + rowb + 16) * IDIM + l16 * 8;
    gB10 = w2b + ((size_t)e * HDIM + rowb + 32) * IDIM + l16 * 8;
    gB11 = w2b + ((size_t)e * HDIM + rowb + 48) * IDIM + l16 * 8;
  }

  f32x4 acc[2][2][4][2];
  #pragma unroll
  for (int qm = 0; qm < 2; ++qm)
    #pragma unroll
    for (int qn = 0; qn < 2; ++qn)
      #pragma unroll
      for (int mi = 0; mi < 4; ++mi)
        #pragma unroll
        for (int ni = 0; ni < 2; ++ni) acc[qm][qn][mi][ni] = (f32x4)(0.0f);

  auto STAGE = [&](int kt) {
    char* d = lds + (kt & 3) * 16384 + wid * 1024;
    GLOAD_LDS16(gA0 + kt * 32, d);
    GLOAD_LDS16(gA1 + kt * 32, d + 8192);
  };

  bf16x8 A0a[4], A1a[4], A0b[4], A1b[4];
  bf16x8 Bc[2][2], Bn[2][2];

  GEMM_BODY();

  // epilogue: contiguous bf16 stores at sorted position, scaled by router coef
  #pragma unroll
  for (int qm = 0; qm < 2; ++qm)
    #pragma unroll
    for (int mi = 0; mi < 4; ++mi)
      #pragma unroll
      for (int jj = 0; jj < 4; ++jj) {
        int r = wr * 128 + qm * 64 + mi * 16 + l16 * 4 + jj;
        int rr = row0 + r;
        if (rr < Ne) {
          float cf = pcoef[base + rr];
          #pragma unroll
          for (int qn = 0; qn < 2; ++qn)
            #pragma unroll
            for (int ni = 0; ni < 2; ++ni) {
              int col = n0 + wc * 64 + qn * 32 + ni * 16 + l15;
              yb[(size_t)(base + rr) * HDIM + col] = f2bf(acc[qm][qn][mi][ni][jj] * cf);
            }
        }
      }
}

// ---------------- reduce: out[t] = yb[pinv[2t]] + yb[pinv[2t+1]] ----------------
__global__ __launch_bounds__(256) void reduce2(const unsigned short* __restrict__ yb,
                                               const int* __restrict__ pinv,
                                               float* __restrict__ out) {
  int i = blockIdx.x * 256 + threadIdx.x;
  int t = i >> 8;
  int g = i & 255;
  int p0 = pinv[2 * t], p1 = pinv[2 * t + 1];
  u16x8 a = *((const u16x8*)(yb + (size_t)p0 * HDIM) + g);
  u16x8 b = *((const u16x8*)(yb + (size_t)p1 * HDIM) + g);
  float4 o0, o1;
  o0.x = bf2f(a[0]) + bf2f(b[0]); o0.y = bf2f(a[1]) + bf2f(b[1]);
  o0.z = bf2f(a[2]) + bf2f(b[2]); o0.w = bf2f(a[3]) + bf2f(b[3]);
  o1.x = bf2f(a[4]) + bf2f(b[4]); o1.y = bf2f(a[5]) + bf2f(b[5]);
  o1.z = bf2f(a[6]) + bf2f(b[6]); o1.w = bf2f(a[7]) + bf2f(b[7]);
  float4* dst = (float4*)(out + (size_t)t * HDIM) + g * 2;
  dst[0] = o0; dst[1] = o1;
}

// ---------------- launcher ----------------
extern "C" void kernel_launch(void* const* d_in, const int* in_sizes, int n_in,
                              void* d_out, int out_size, void* d_ws, size_t ws_size,
                              hipStream_t stream) {
  const float* x   = (const float*)d_in[0];
  const int*   ert = (const int*)d_in[1];
  const float* rw  = (const float*)d_in[2];
  const float* w13 = (const float*)d_in[3];
  const float* w2  = (const float*)d_in[4];
  float* out = (float*)d_out;

  char* ws = (char*)d_ws;
  size_t off = 0;
  auto alloc = [&](size_t bytes) { char* p = ws + off; off += (bytes + 255) & ~255ULL; return p; };
  int*            ctrl  = (int*)           alloc(256);
  int*            porig = (int*)           alloc((size_t)NPAIR * 4);
  float*          pcoef = (float*)         alloc((size_t)NPAIR * 4);
  int*            pinv  = (int*)           alloc((size_t)NPAIR * 4);
  unsigned short* w2b   = (unsigned short*)alloc((size_t)NEXP * HDIM * IDIM * 2);
  unsigned short* actb  = (unsigned short*)alloc((size_t)NPAIR * IDIM * 2);
  unsigned short* w13b  = (unsigned short*)alloc((size_t)NEXP * 2 * IDIM * HDIM * 2);
  unsigned short* xb    = (unsigned short*)alloc((size_t)TOKS * HDIM * 2);
  // yb (NPAIR x HDIM bf16 = 128 MiB) overlays w13b (dead after gemm1)
  unsigned short* yb    = w13b;

  hipMemsetAsync(ctrl, 0, 256, stream);

  cvt_all<<<(W13_N8 + W2_N8 + X_N8) / 256, 256, 0, stream>>>(w13, w2, x, w13b, w2b, xb);

  route_count  <<<NPAIR / 256, 256, 0, stream>>>(ert, ctrl);
  route_scan   <<<1, 64, 0, stream>>>(ctrl);
  route_scatter<<<NPAIR / 256, 256, 0, stream>>>(ert, rw, ctrl, porig, pcoef, pinv);

  gemm1<<<136 * 8, 512, 0, stream>>>(xb, w13b, ctrl, porig, actb);
  gemm2<<<136 * 8, 512, 0, stream>>>(actb, w2b, ctrl, pcoef, yb);
  reduce2<<<(TOKS * HDIM / 8) / 256, 256, 0, stream>>>(yb, pinv, out);
}

// Round 14
// 837.331 us; speedup vs baseline: 1.3346x; 1.3346x over previous
//
#include <hip/hip_runtime.h>
#include <hip/hip_bf16.h>
#include <stdint.h>

#define TOKS 16384
#define HDIM 2048
#define IDIM 1024
#define NEXP 8
#define TOPK 2
#define NPAIR (TOKS*TOPK)   // 32768

typedef __attribute__((ext_vector_type(4))) float f32x4;
typedef __attribute__((ext_vector_type(8))) __bf16 bf16x8;
typedef __attribute__((ext_vector_type(8))) unsigned short u16x8;

#define GLOAD_LDS16(gp, lp) \
  __builtin_amdgcn_global_load_lds((const __attribute__((address_space(1))) void*)(gp), \
                                   (__attribute__((address_space(3))) void*)(lp), 16, 0, 0)

#define LGKM_WAITN(n) asm volatile("s_waitcnt lgkmcnt(" #n ")" ::: "memory")
#define VM_WAITN(n)   asm volatile("s_waitcnt vmcnt(" #n ")" ::: "memory")
#define SBAR0()       __builtin_amdgcn_sched_barrier(0)

__device__ __forceinline__ unsigned short f2bf(float f) {
  unsigned int u = __float_as_uint(f);
  u += 0x7FFF + ((u >> 16) & 1);   // RNE
  return (unsigned short)(u >> 16);
}
__device__ __forceinline__ float bf2f(unsigned short h) {
  return __uint_as_float(((unsigned int)h) << 16);
}

// ---------------- fused conversion: f32 -> bf16 for w13, w2, x ----------------
#define W13_N8 (NEXP * 2 * IDIM * HDIM / 8)   // 4194304
#define W2_N8  (NEXP * HDIM * IDIM / 8)       // 2097152
#define X_N8   (TOKS * HDIM / 8)              // 4194304
__global__ __launch_bounds__(256) void cvt_all(const float* __restrict__ w13,
                                               const float* __restrict__ w2,
                                               const float* __restrict__ x,
                                               unsigned short* __restrict__ w13b,
                                               unsigned short* __restrict__ w2b,
                                               unsigned short* __restrict__ xb) {
  int i = blockIdx.x * 256 + threadIdx.x;
  const float* s; unsigned short* d; int j;
  if (i < W13_N8)              { s = w13; d = w13b; j = i; }
  else if (i < W13_N8 + W2_N8) { s = w2;  d = w2b;  j = i - W13_N8; }
  else                         { s = x;   d = xb;   j = i - W13_N8 - W2_N8; }
  const float4* sp = (const float4*)s + (size_t)j * 2;
  float4 a = sp[0], b = sp[1];
  u16x8 o;
  o[0] = f2bf(a.x); o[1] = f2bf(a.y); o[2] = f2bf(a.z); o[3] = f2bf(a.w);
  o[4] = f2bf(b.x); o[5] = f2bf(b.y); o[6] = f2bf(b.z); o[7] = f2bf(b.w);
  *((u16x8*)d + j) = o;
}

// ---------------- routing ----------------
// ctrl ints: [0..7]=counts [8..15]=offsets [16..23]=cursors [24..31]=rowtile prefix [32]=total tiles
__global__ void route_count(const int* __restrict__ ert, int* __restrict__ ctrl) {
  int p = blockIdx.x * 256 + threadIdx.x;
  if (p < NPAIR) atomicAdd(&ctrl[ert[p]], 1);
}

__global__ void route_scan(int* __restrict__ ctrl) {
  if (blockIdx.x == 0 && threadIdx.x == 0) {
    int off = 0;
    for (int e = 0; e < NEXP; ++e) { ctrl[8 + e] = off; ctrl[16 + e] = off; off += ctrl[e]; }
    int toff = 0;
    for (int e = 0; e < NEXP; ++e) { ctrl[24 + e] = toff; toff += (ctrl[e] + 255) >> 8; }
    ctrl[32] = toff;
  }
}

__global__ void route_scatter(const int* __restrict__ ert, const float* __restrict__ rw,
                              int* __restrict__ ctrl, int* __restrict__ porig,
                              float* __restrict__ pcoef, int* __restrict__ pinv) {
  int p = blockIdx.x * 256 + threadIdx.x;
  if (p < NPAIR) {
    int e = ert[p];
    int pos = atomicAdd(&ctrl[16 + e], 1);
    porig[pos] = p;
    pcoef[pos] = rw[p];
    pinv[p]    = pos;
  }
}

// ===== GEMM: 256x256 tile, 8 waves (2M x 4N), per-wave 128x64, BK=32.
// m201-style 4-phase schedule: every ds_read batch is issued ONE PHASE AHEAD
// of its consuming MFMA quadrant and drains under the current quadrant's
// MFMAs (counted lgkm never waits on the just-issued batch). 2 barriers per
// K-tile; counted vmcnt(2) (never 0 mid-loop). Single-buffered frag regs
// (A0/A1/B0/B1 = 48 VGPR) keep total ~210 unified regs -> 2 waves/SIMD.
// LDS: dbuf[2] x (A 256x32 @0, B 256x32 @16K) = 64 KB. Row = 64B = 4x16B
// slots, slot XOR (row>>1)&3, source pre-swizzled (same involution).
// Stage slots (1 gload = 1 half = 128 rows x 32k = 8KB):
//   ph0(s): Bh0(s+1), ph1(s): Bh1(s+1), ph2(s): Ah0(s+2), ph3(s): Ah1(s+2).
// vmcnt ledger at ph3(s): outstanding = [Ah0(s+1)@ph2(s-1), Ah1(s+1)@ph3(s-1),
//   Bh0(s+1)@ph0(s), Bh1(s+1)@ph1(s), Ah0(s+2)@ph2(s), Ah1(s+2)@ph3(s)] = 6
//   -> VM(2) retires tile s+1 exactly; then barrier (cross-wave visibility,
//   round-8 ordering) then reads. Tail: VM(0) at s=NT-2; skip at s=NT-1.
// WAR: all stages of tile s+2 sit behind ph2(s)'s barrier, which each wave
//   crosses only after lgkm(0) proves its tile-s reads retired.
// lgkm ledger (reads/tile: A0:4, B0:2 @ph3(s-1); B1:2 @ph0; A1:4 @ph1):
//   ph0: 6+2 outstanding -> LGKM(2) = A0,B0 ready (B1 flying under q00)
//   ph1: 2+4 -> LGKM(4) = B1 ready (A1 flying under q01)
//   ph2: LGKM(0) = A1 ready.  ph3: all in regs; q11 covers next A0/B0 reads.

#define RD_A0(lb) do { _Pragma("unroll") for (int mi = 0; mi < 4; ++mi) {            \
    int r_ = wr * 128 + mi * 16 + l15;                                               \
    fA0[mi] = *(const bf16x8*)((lb) + r_ * 64 + ((l16 ^ ((r_ >> 1) & 3)) << 4)); } } while (0)
#define RD_A1(lb) do { _Pragma("unroll") for (int mi = 0; mi < 4; ++mi) {            \
    int r_ = wr * 128 + 64 + mi * 16 + l15;                                          \
    fA1[mi] = *(const bf16x8*)((lb) + r_ * 64 + ((l16 ^ ((r_ >> 1) & 3)) << 4)); } } while (0)
#define RD_B0(lb) do { _Pragma("unroll") for (int ni = 0; ni < 2; ++ni) {            \
    int rn_ = wc * 64 + ni * 16 + l15;                                               \
    fB0[ni] = *(const bf16x8*)((lb) + 16384 + rn_ * 64 + ((l16 ^ ((rn_ >> 1) & 3)) << 4)); } } while (0)
#define RD_B1(lb) do { _Pragma("unroll") for (int ni = 0; ni < 2; ++ni) {            \
    int rn_ = wc * 64 + 32 + ni * 16 + l15;                                          \
    fB1[ni] = *(const bf16x8*)((lb) + 16384 + rn_ * 64 + ((l16 ^ ((rn_ >> 1) & 3)) << 4)); } } while (0)

#define MMQ(qm, qn, Av, Bv) do {                                                     \
  __builtin_amdgcn_s_setprio(1);                                                     \
  _Pragma("unroll") for (int mi = 0; mi < 4; ++mi)                                   \
    _Pragma("unroll") for (int ni = 0; ni < 2; ++ni)                                 \
      acc[qm][qn][mi][ni] = __builtin_amdgcn_mfma_f32_16x16x32_bf16(                 \
          Av[mi], Bv[ni], acc[qm][qn][mi][ni], 0, 0, 0);                             \
  __builtin_amdgcn_s_setprio(0);                                                     \
} while (0)

#define STAGE_A(kt, h) GLOAD_LDS16(gA[h] + (size_t)(kt) * 32,                        \
    lds + ((kt) & 1) * 32768 + (h) * 8192 + wid * 1024)
#define STAGE_B(kt, h) GLOAD_LDS16(gB[h] + (size_t)(kt) * 32,                        \
    lds + ((kt) & 1) * 32768 + 16384 + (h) * 8192 + wid * 1024)

#define GEMM_LOOP() do {                                                             \
  STAGE_A(0, 0); STAGE_A(0, 1); STAGE_B(0, 0); STAGE_B(0, 1);                        \
  STAGE_A(1, 0); STAGE_A(1, 1);                                                      \
  VM_WAITN(2);                       /* retire tile 0 (keep t1 A-halves) */          \
  __builtin_amdgcn_s_barrier(); SBAR0();                                             \
  RD_A0(lds); RD_B0(lds); SBAR0();                                                   \
  for (int s = 0; s < NT; ++s) {                                                     \
    const char* lbc = lds + (s & 1) * 32768;                                         \
    const char* lbn = lds + ((s + 1) & 1) * 32768;                                   \
    /* ph0 */                                                                        \
    if (s + 1 < NT) STAGE_B(s + 1, 0);                                               \
    RD_B1(lbc); SBAR0();                                                             \
    LGKM_WAITN(2); SBAR0();                                                          \
    MMQ(0, 0, fA0, fB0);                                                             \
    /* ph1 */                                                                        \
    if (s + 1 < NT) STAGE_B(s + 1, 1);                                               \
    RD_A1(lbc); SBAR0();                                                             \
    LGKM_WAITN(4); SBAR0();                                                          \
    MMQ(0, 1, fA0, fB1);                                                             \
    /* ph2 */                                                                        \
    LGKM_WAITN(0); SBAR0();                                                          \
    __builtin_amdgcn_s_barrier();                                                    \
    if (s + 2 < NT) STAGE_A(s + 2, 0);                                               \
    MMQ(1, 0, fA1, fB0);                                                             \
    /* ph3 */                                                                        \
    if (s + 2 < NT) STAGE_A(s + 2, 1);                                               \
    if (s + 1 < NT) {                                                                \
      if (s + 2 < NT) { VM_WAITN(2); } else { VM_WAITN(0); }                         \
      SBAR0();                                                                       \
      __builtin_amdgcn_s_barrier();                                                  \
      RD_A0(lbn); RD_B0(lbn); SBAR0();                                               \
    }                                                                                \
    MMQ(1, 1, fA1, fB1);                                                             \
  }                                                                                  \
} while (0)

// XCD-co-located block map: the 8 cb-blocks of one tile occupy 8 consecutive
// dispatch slots of the SAME XCD (bid = x + 8*(tg*8+cb), tile = tg*8+x).
#define TILE_MAP()                                                                   \
  const int x_ = bid & 7, k_ = bid >> 3;                                             \
  const int cb = k_ & 7;                                                             \
  const int tile = ((k_ >> 3) << 3) + x_;

// ============ GEMM1: act = silu(x@Wg^T)*(x@Wu^T) ============
__global__ __launch_bounds__(512, 2) void gemm1(const unsigned short* __restrict__ xb,
                                                const unsigned short* __restrict__ w13b,
                                                const int* __restrict__ ctrl,
                                                const int* __restrict__ porig,
                                                unsigned short* __restrict__ actb) {
  __shared__ __align__(16) char lds[65536];
  const int bid  = blockIdx.x;
  TILE_MAP();
  if (tile >= ctrl[32]) return;
  int e = 7;
  #pragma unroll
  for (int k = 7; k >= 1; --k) if (tile < ctrl[24 + k]) e = k - 1;
  const int Ne   = ctrl[e];
  const int base = ctrl[8 + e];
  const int row0 = (tile - ctrl[24 + e]) * 256;
  const int c0   = cb * 128;
  const int tid  = threadIdx.x;
  const int wid  = tid >> 6;
  const int lane = tid & 63;
  const int wr   = wid >> 2;          // 0..1
  const int wc   = wid & 3;           // 0..3
  const int l15  = lane & 15;
  const int l16  = lane >> 4;
  const int NT   = HDIM / 32;         // 64

  // staging pointers (source pre-swizzled): half h, row = h*128 + tid/4,
  // 16B-slot = (tid&3) ^ ((row>>1)&3)
  const unsigned short *gA[2], *gB[2];
  #pragma unroll
  for (int h = 0; h < 2; ++h) {
    int r  = h * 128 + (tid >> 2);
    int c8 = (tid & 3) ^ ((r >> 1) & 3);
    int rr = row0 + r; if (rr > Ne - 1) rr = Ne - 1;
    gA[h] = xb + (size_t)(porig[base + rr] >> 1) * HDIM + c8 * 8;
    // B row r: gate/up interleave (n&32 -> up half of w13)
    int n  = r & 63;
    int gr = ((n & 32) ? IDIM : 0) + c0 + ((r >> 6) << 5) + (n & 31);
    gB[h] = w13b + ((size_t)e * (2 * IDIM) + gr) * HDIM + c8 * 8;
  }

  f32x4 acc[2][2][4][2];
  #pragma unroll
  for (int qm = 0; qm < 2; ++qm)
    #pragma unroll
    for (int qn = 0; qn < 2; ++qn)
      #pragma unroll
      for (int mi = 0; mi < 4; ++mi)
        #pragma unroll
        for (int ni = 0; ni < 2; ++ni) acc[qm][qn][mi][ni] = (f32x4)(0.0f);

  bf16x8 fA0[4], fA1[4], fB0[2], fB1[2];
  GEMM_LOOP();

  // epilogue: silu(gate)*up -> bf16 act (qn=0 gate, qn=1 up, same cols)
  #pragma unroll
  for (int qm = 0; qm < 2; ++qm)
    #pragma unroll
    for (int mi = 0; mi < 4; ++mi)
      #pragma unroll
      for (int jj = 0; jj < 4; ++jj) {
        int r = wr * 128 + qm * 64 + mi * 16 + l16 * 4 + jj;
        int rr = row0 + r;
        if (rr < Ne) {
          #pragma unroll
          for (int ni = 0; ni < 2; ++ni) {
            float g = acc[qm][0][mi][ni][jj];
            float u = acc[qm][1][mi][ni][jj];
            float a = g / (1.0f + __expf(-g)) * u;
            actb[(size_t)(base + rr) * IDIM + (c0 + wc * 32 + ni * 16 + l15)] = f2bf(a);
          }
        }
      }
}

// ============ GEMM2: yb[pos] = coef * (act @ w2^T) ============
__global__ __launch_bounds__(512, 2) void gemm2(const unsigned short* __restrict__ actb,
                                                const unsigned short* __restrict__ w2b,
                                                const int* __restrict__ ctrl,
                                                const float* __restrict__ pcoef,
                                                unsigned short* __restrict__ yb) {
  __shared__ __align__(16) char lds[65536];
  const int bid  = blockIdx.x;
  TILE_MAP();
  if (tile >= ctrl[32]) return;
  int e = 7;
  #pragma unroll
  for (int k = 7; k >= 1; --k) if (tile < ctrl[24 + k]) e = k - 1;
  const int Ne   = ctrl[e];
  const int base = ctrl[8 + e];
  const int row0 = (tile - ctrl[24 + e]) * 256;
  const int n0   = cb * 256;
  const int tid  = threadIdx.x;
  const int wid  = tid >> 6;
  const int lane = tid & 63;
  const int wr   = wid >> 2;
  const int wc   = wid & 3;
  const int l15  = lane & 15;
  const int l16  = lane >> 4;
  const int NT   = IDIM / 32;         // 32

  const unsigned short *gA[2], *gB[2];
  #pragma unroll
  for (int h = 0; h < 2; ++h) {
    int r  = h * 128 + (tid >> 2);
    int c8 = (tid & 3) ^ ((r >> 1) & 3);
    int rr = row0 + r; if (rr > Ne - 1) rr = Ne - 1;
    gA[h] = actb + (size_t)(base + rr) * IDIM + c8 * 8;
    gB[h] = w2b + ((size_t)e * HDIM + n0 + r) * IDIM + c8 * 8;
  }

  f32x4 acc[2][2][4][2];
  #pragma unroll
  for (int qm = 0; qm < 2; ++qm)
    #pragma unroll
    for (int qn = 0; qn < 2; ++qn)
      #pragma unroll
      for (int mi = 0; mi < 4; ++mi)
        #pragma unroll
        for (int ni = 0; ni < 2; ++ni) acc[qm][qn][mi][ni] = (f32x4)(0.0f);

  bf16x8 fA0[4], fA1[4], fB0[2], fB1[2];
  GEMM_LOOP();

  // epilogue: contiguous bf16 stores at sorted position, scaled by router coef
  #pragma unroll
  for (int qm = 0; qm < 2; ++qm)
    #pragma unroll
    for (int mi = 0; mi < 4; ++mi)
      #pragma unroll
      for (int jj = 0; jj < 4; ++jj) {
        int r = wr * 128 + qm * 64 + mi * 16 + l16 * 4 + jj;
        int rr = row0 + r;
        if (rr < Ne) {
          float cf = pcoef[base + rr];
          #pragma unroll
          for (int qn = 0; qn < 2; ++qn)
            #pragma unroll
            for (int ni = 0; ni < 2; ++ni) {
              int col = n0 + wc * 64 + qn * 32 + ni * 16 + l15;
              yb[(size_t)(base + rr) * HDIM + col] = f2bf(acc[qm][qn][mi][ni][jj] * cf);
            }
        }
      }
}

// ---------------- reduce: out[t] = yb[pinv[2t]] + yb[pinv[2t+1]] ----------------
__global__ __launch_bounds__(256) void reduce2(const unsigned short* __restrict__ yb,
                                               const int* __restrict__ pinv,
                                               float* __restrict__ out) {
  int i = blockIdx.x * 256 + threadIdx.x;
  int t = i >> 8;
  int g = i & 255;
  int p0 = pinv[2 * t], p1 = pinv[2 * t + 1];
  u16x8 a = *((const u16x8*)(yb + (size_t)p0 * HDIM) + g);
  u16x8 b = *((const u16x8*)(yb + (size_t)p1 * HDIM) + g);
  float4 o0, o1;
  o0.x = bf2f(a[0]) + bf2f(b[0]); o0.y = bf2f(a[1]) + bf2f(b[1]);
  o0.z = bf2f(a[2]) + bf2f(b[2]); o0.w = bf2f(a[3]) + bf2f(b[3]);
  o1.x = bf2f(a[4]) + bf2f(b[4]); o1.y = bf2f(a[5]) + bf2f(b[5]);
  o1.z = bf2f(a[6]) + bf2f(b[6]); o1.w = bf2f(a[7]) + bf2f(b[7]);
  float4* dst = (float4*)(out + (size_t)t * HDIM) + g * 2;
  dst[0] = o0; dst[1] = o1;
}

// ---------------- launcher ----------------
extern "C" void kernel_launch(void* const* d_in, const int* in_sizes, int n_in,
                              void* d_out, int out_size, void* d_ws, size_t ws_size,
                              hipStream_t stream) {
  const float* x   = (const float*)d_in[0];
  const int*   ert = (const int*)d_in[1];
  const float* rw  = (const float*)d_in[2];
  const float* w13 = (const float*)d_in[3];
  const float* w2  = (const float*)d_in[4];
  float* out = (float*)d_out;

  char* ws = (char*)d_ws;
  size_t off = 0;
  auto alloc = [&](size_t bytes) { char* p = ws + off; off += (bytes + 255) & ~255ULL; return p; };
  int*            ctrl  = (int*)           alloc(256);
  int*            porig = (int*)           alloc((size_t)NPAIR * 4);
  float*          pcoef = (float*)         alloc((size_t)NPAIR * 4);
  int*            pinv  = (int*)           alloc((size_t)NPAIR * 4);
  unsigned short* w2b   = (unsigned short*)alloc((size_t)NEXP * HDIM * IDIM * 2);
  unsigned short* actb  = (unsigned short*)alloc((size_t)NPAIR * IDIM * 2);
  unsigned short* w13b  = (unsigned short*)alloc((size_t)NEXP * 2 * IDIM * HDIM * 2);
  unsigned short* xb    = (unsigned short*)alloc((size_t)TOKS * HDIM * 2);
  // yb (NPAIR x HDIM bf16 = 128 MiB) overlays w13b (dead after gemm1)
  unsigned short* yb    = w13b;

  hipMemsetAsync(ctrl, 0, 256, stream);

  cvt_all<<<(W13_N8 + W2_N8 + X_N8) / 256, 256, 0, stream>>>(w13, w2, x, w13b, w2b, xb);

  route_count  <<<NPAIR / 256, 256, 0, stream>>>(ert, ctrl);
  route_scan   <<<1, 64, 0, stream>>>(ctrl);
  route_scatter<<<NPAIR / 256, 256, 0, stream>>>(ert, rw, ctrl, porig, pcoef, pinv);

  gemm1<<<136 * 8, 512, 0, stream>>>(xb, w13b, ctrl, porig, actb);
  gemm2<<<136 * 8, 512, 0, stream>>>(actb, w2b, ctrl, pcoef, yb);
  reduce2<<<(TOKS * HDIM / 8) / 256, 256, 0, stream>>>(yb, pinv, out);
}